// Round 6
// baseline (212.008 us; speedup 1.0000x reference)
//
#include <hip/hip_runtime.h>
#include <cstdint>
#include <cstddef>

#define HH 2048
#define WW 2048
#define NPIX (HH * WW)
#define EPS_NMS 1e-5f
#define EPS_DIV 1e-8f
#define NEG_INF (-3.402823466e+38f)
#define ROWS 4          // rows per block (block covers 1024 cols x ROWS rows)
#define LCAP 1024       // per-block candidate cap; >= max density (1 per 2x2)
#define SG_CAP 8192     // max selected (top22 >= T22) keys
#define NBIN 2048       // 11-bit radix bins
#define SEL_BLOCKS 64   // co-resident: 64 blocks x 4 waves << 8192-wave capacity

typedef unsigned long long u64;

// ---- workspace layout (bytes) ----
// [0,   128)    : uint32 cnt[32]  0=n_cand 1=n_sel 3=prefix/T22 16..20=grid barrier ctrs
// [128, 8320)   : uint32 hist[2048]
// [16384,81920) : SG u64[8192]  (all keys with top22 >= T22, unsorted)
// [81920, ...)  : candidates u64[cap]

__device__ __forceinline__ float max3(float a, float b, float c) {
    return fmaxf(a, fmaxf(b, c));
}

__device__ __forceinline__ unsigned int aload(const unsigned int* p) {
    return __hip_atomic_load(p, __ATOMIC_RELAXED, __HIP_MEMORY_SCOPE_AGENT);
}

// grid barrier for exactly SEL_BLOCKS co-resident blocks; ctr pre-zeroed, single-use
__device__ __forceinline__ void gbar(unsigned int* ctr) {
    __syncthreads();
    if (threadIdx.x == 0) {
        __threadfence();                      // drain+wbL2: plain stores visible device-wide
        atomicAdd(ctr, 1u);
        while (aload(ctr) < (unsigned int)SEL_BLOCKS) {}
        __threadfence();
    }
    __syncthreads();
}

// Block: 256 threads x 4 cols = 1024 cols, ROWS rows. ALL tile loads issued
// up front into register arrays (MLP); horizontal halo via wave shfl.
// blockIdx.y==0 blocks additionally zero the vals+lafs output region.
__global__ __launch_bounds__(256) void nms_map_kernel(
    const float* __restrict__ low, const float* __restrict__ cur,
    const float* __restrict__ high, const float* __restrict__ oct,
    float* __restrict__ oct_out, float* __restrict__ vals_out, int n7k,
    u64* __restrict__ cand, unsigned int* __restrict__ cnt, unsigned int cap)
{
    __shared__ unsigned int lcount, lbase;
    __shared__ u64 lcand[LCAP];

    const int tid = threadIdx.x;
    const int lane = tid & 63;
    const int x4 = blockIdx.x * 1024 + tid * 4;
    const int y0 = blockIdx.y * ROWS;
    if (tid == 0) lcount = 0u;

    if (blockIdx.y == 0) {                    // fold in out-region zeroing
        int n4 = n7k >> 2;
        float4* vz = (float4*)vals_out;
        for (int i = blockIdx.x * 256 + tid; i < n4; i += gridDim.x * 256)
            vz[i] = make_float4(0.f, 0.f, 0.f, 0.f);
    }
    __syncthreads();

    // ---- phase 1: issue ALL z-cube loads (6 rows x 3 arrays) up front ----
    float4 L[ROWS + 2], C[ROWS + 2], Hi[ROWS + 2];
    float eL[ROWS + 2][3], eR[ROWS + 2][3];
    #pragma unroll
    for (int r = 0; r < ROWS + 2; ++r) {
        int t = y0 - 1 + r;
        bool valid = (t >= 0) && (t < HH);
        int jj = valid ? (t * WW + x4) : 0;
        if (valid) {
            L[r]  = *(const float4*)(low + jj);
            C[r]  = *(const float4*)(cur + jj);
            Hi[r] = *(const float4*)(high + jj);
        } else {
            L[r] = C[r] = Hi[r] = make_float4(NEG_INF, NEG_INF, NEG_INF, NEG_INF);
        }
        bool doL = valid && (lane == 0) && (x4 > 0);
        bool doR = valid && (lane == 63) && (x4 + 4 < WW);
        eL[r][0] = doL ? low[jj - 1]  : NEG_INF;
        eL[r][1] = doL ? cur[jj - 1]  : NEG_INF;
        eL[r][2] = doL ? high[jj - 1] : NEG_INF;
        eR[r][0] = doR ? low[jj + 4]  : NEG_INF;
        eR[r][1] = doR ? cur[jj + 4]  : NEG_INF;
        eR[r][2] = doR ? high[jj + 4] : NEG_INF;
    }
    float4 O[ROWS];
    #pragma unroll
    for (int j = 0; j < ROWS; ++j)
        O[j] = *(const float4*)(oct + (y0 + j) * WW + x4);

    // ---- phase 2: horizontal 3-window max of z-max per row ----
    float4 hz[ROWS + 2], cv[ROWS + 2];
    #pragma unroll
    for (int r = 0; r < ROWS + 2; ++r) {
        int t = y0 - 1 + r;
        bool valid = (t >= 0) && (t < HH);
        float4 z;
        z.x = max3(L[r].x, C[r].x, Hi[r].x);
        z.y = max3(L[r].y, C[r].y, Hi[r].y);
        z.z = max3(L[r].z, C[r].z, Hi[r].z);
        z.w = max3(L[r].w, C[r].w, Hi[r].w);
        float zeL = max3(eL[r][0], eL[r][1], eL[r][2]);
        float zeR = max3(eR[r][0], eR[r][1], eR[r][2]);
        float zl = __shfl_up(z.w, 1, 64);
        float zr = __shfl_down(z.x, 1, 64);
        if (lane == 0)  zl = zeL;
        if (lane == 63) zr = zeR;
        if (valid) {
            hz[r].x = max3(zl,  z.x, z.y);
            hz[r].y = max3(z.x, z.y, z.z);
            hz[r].z = max3(z.y, z.z, z.w);
            hz[r].w = max3(z.z, z.w, zr);
            cv[r] = C[r];
        } else {
            hz[r] = make_float4(NEG_INF, NEG_INF, NEG_INF, NEG_INF);
            cv[r] = make_float4(0.f, 0.f, 0.f, 0.f);
        }
    }

    // ---- phase 3: NMS + octave update + candidate push ----
    #pragma unroll
    for (int j = 0; j < ROWS; ++j) {
        int y = y0 + j;
        int idx = y * WW + x4;
        float4 o = O[j];
        float4 c1 = cv[j + 1];
        bool yin = (y > 0) && (y < HH - 1);
        float4 ov;
        #define DO_COMP(comp, i)  {                                               \
            float m = max3(hz[j].comp, hz[j + 1].comp, hz[j + 2].comp);           \
            int xg = x4 + (i);                                                    \
            bool interior = yin && (xg > 0) && (xg < WW - 1);                     \
            float nm = (((c1.comp - m + EPS_NMS) > 0.0f) && interior)             \
                       ? c1.comp * (1.0f - o.comp) : 0.0f;                        \
            ov.comp = (float)((unsigned char)(o.comp + nm));                      \
            if (nm > 0.0f) {                                                      \
                unsigned int p = atomicAdd(&lcount, 1u);                          \
                if (p < LCAP)                                                     \
                    lcand[p] = (((u64)__float_as_uint(nm)) << 32)                 \
                               | (unsigned int)(~(idx + (i)));                    \
            }                                                                     \
        }
        DO_COMP(x, 0) DO_COMP(y, 1) DO_COMP(z, 2) DO_COMP(w, 3)
        #undef DO_COMP
        *(float4*)(oct_out + idx) = ov;
    }

    __syncthreads();
    unsigned int c = lcount < LCAP ? lcount : LCAP;
    if (tid == 0) lbase = atomicAdd(cnt, c);
    __syncthreads();
    unsigned int base = lbase;
    for (unsigned int i = tid; i < c; i += 256) {
        unsigned int p = base + i;
        if (p < cap) cand[p] = lcand[i];
    }
}

// Fused exact top-K threshold select: 2 x 11-bit radix passes + compact,
// one launch, SEL_BLOCKS co-resident blocks, spin grid barriers.
__global__ __launch_bounds__(256) void select_kernel(
    const u64* __restrict__ cand, u64* __restrict__ SG,
    unsigned int* __restrict__ cnt, unsigned int* __restrict__ hist,
    unsigned int cap, int K)
{
    __shared__ unsigned int h[NBIN];
    __shared__ unsigned int s[256];
    __shared__ unsigned int sh_prefix, sh_remk;
    __shared__ unsigned int lc, lb;
    __shared__ u64 buf[2048];
    const int tid = threadIdx.x;
    const int bid = blockIdx.x;
    unsigned int* bar = cnt + 16;
    unsigned int n = cnt[0]; if (n > cap) n = cap;
    const unsigned int stride = SEL_BLOCKS * 256;

    // A: zero global hist (blocks 0..7), local hist; no barrier yet
    int gtid = bid * 256 + tid;
    if (gtid < NBIN) hist[gtid] = 0u;
    for (int i = tid; i < NBIN; i += 256) h[i] = 0u;
    __syncthreads();

    // B: pass-0 local hist on top 11 bits of value
    for (unsigned int i = bid * 256 + tid; i < n; i += stride)
        atomicAdd(&h[(unsigned int)(cand[i] >> 53)], 1u);
    gbar(&bar[0]);                                     // zeros visible before merge
    // D: merge
    for (int i = tid; i < NBIN; i += 256) { unsigned int v = h[i]; if (v) atomicAdd(&hist[i], v); }
    gbar(&bar[1]);

    // F: pick pass 0 (block 0); thread t owns bins [t*8, t*8+8)
    if (bid == 0) {
        unsigned int bins[8], csum = 0;
        #pragma unroll
        for (int i = 0; i < 8; ++i) { bins[i] = aload(&hist[tid * 8 + i]); csum += bins[i]; }
        s[tid] = csum;
        __syncthreads();
        for (int off = 1; off < 256; off <<= 1) {
            unsigned int v = (tid + off < 256) ? s[tid + off] : 0u;
            __syncthreads(); s[tid] += v; __syncthreads();
        }
        unsigned int remk = (unsigned int)K;
        unsigned int incl = s[tid], excl = incl - csum, total = s[0];
        if (incl >= remk && excl < remk) {
            unsigned int cum = excl; int b = 7;
            for (; b > 0; --b) { cum += bins[b]; if (cum >= remk) break; }
            if (cum < remk) cum += bins[0];
            sh_prefix = (unsigned int)(tid * 8 + b);
            sh_remk   = remk - (cum - bins[b]);
        }
        if (tid == 0 && total < remk) { sh_prefix = 0u; sh_remk = remk; }
        __syncthreads();
        for (int i = tid; i < NBIN; i += 256) hist[i] = 0u;   // re-zero for pass 1
        __syncthreads();
        if (tid == 0) atomicExch(&cnt[3], sh_prefix);          // publish prefix
    }
    gbar(&bar[2]);

    // H: pass-1 local hist on next 11 bits, gated by prefix
    unsigned int prefix = aload(&cnt[3]);
    for (int i = tid; i < NBIN; i += 256) h[i] = 0u;
    __syncthreads();
    for (unsigned int i = bid * 256 + tid; i < n; i += stride) {
        unsigned int k32 = (unsigned int)(cand[i] >> 32);
        if ((k32 >> 21) == prefix) atomicAdd(&h[(k32 >> 10) & (NBIN - 1u)], 1u);
    }
    __syncthreads();
    for (int i = tid; i < NBIN; i += 256) { unsigned int v = h[i]; if (v) atomicAdd(&hist[i], v); }
    gbar(&bar[3]);

    // J: pick pass 1 (block 0) -> T22
    if (bid == 0) {
        unsigned int bins[8], csum = 0;
        #pragma unroll
        for (int i = 0; i < 8; ++i) { bins[i] = aload(&hist[tid * 8 + i]); csum += bins[i]; }
        s[tid] = csum;
        __syncthreads();
        for (int off = 1; off < 256; off <<= 1) {
            unsigned int v = (tid + off < 256) ? s[tid + off] : 0u;
            __syncthreads(); s[tid] += v; __syncthreads();
        }
        unsigned int remk = sh_remk, pfx = sh_prefix;
        unsigned int incl = s[tid], excl = incl - csum, total = s[0];
        __shared__ unsigned int sh_T;
        if (tid == 0) sh_T = pfx << 11;                        // degenerate default
        __syncthreads();
        if (incl >= remk && excl < remk) {
            unsigned int cum = excl; int b = 7;
            for (; b > 0; --b) { cum += bins[b]; if (cum >= remk) break; }
            if (cum < remk) cum += bins[0];
            sh_T = (pfx << 11) | (unsigned int)(tid * 8 + b);
        }
        __syncthreads();
        if (tid == 0) atomicExch(&cnt[3], sh_T);               // publish T22
    }
    gbar(&bar[4]);

    // L: compact all keys with top22 >= T22 into SG
    unsigned int T = aload(&cnt[3]);
    if (tid == 0) lc = 0u;
    __syncthreads();
    for (unsigned int i = bid * 256 + tid; i < n; i += stride) {
        u64 key = cand[i];
        if ((unsigned int)(key >> 42) >= T) {
            unsigned int p = atomicAdd(&lc, 1u);
            if (p < 2048u) buf[p] = key;
        }
    }
    __syncthreads();
    unsigned int c = lc < 2048u ? lc : 2048u;
    if (tid == 0) lb = atomicAdd(&cnt[1], c);
    __syncthreads();
    unsigned int base = lb;
    for (unsigned int i = tid; i < c; i += 256) {
        unsigned int p = base + i;
        if (p < SG_CAP) SG[p] = buf[i];
    }
}

// one WAVE per element: lanes partial-count exact 64-bit rank over coalesced
// L2-resident SG, shfl-reduce, lane 0 does the centroid fit + LAF write.
__global__ __launch_bounds__(256) void rank_finalize_kernel(
    const u64* __restrict__ SG, const unsigned int* __restrict__ cnt,
    const float* __restrict__ low, const float* __restrict__ cur,
    const float* __restrict__ high, const float* __restrict__ aff,
    float* __restrict__ out, int K)
{
    unsigned int m = cnt[1]; if (m > SG_CAP) m = SG_CAP;
    unsigned int wave = threadIdx.x >> 6;
    unsigned int lane = threadIdx.x & 63u;
    unsigned int e = blockIdx.x * 4 + wave;
    if (e >= m) return;
    u64 my = SG[e];

    unsigned int rank = 0;
    for (unsigned int j = lane; j < m; j += 64)
        rank += (unsigned)(SG[j] > my);
    #pragma unroll
    for (int off = 32; off > 0; off >>= 1)
        rank += __shfl_down(rank, off, 64);
    if (lane != 0) return;
    if (rank >= (unsigned int)K) return;

    float val = __uint_as_float((unsigned int)(my >> 32));
    unsigned int idx = ~((unsigned int)my);
    out[rank] = val;
    float* laf = out + K + (size_t)rank * 6;
    int y = (int)(idx >> 11), x = (int)(idx & (WW - 1));
    const float ccw[3] = {-0.5f, 0.5f, 1.5f};
    float den = 0.0f, nz = 0.0f, ny = 0.0f, nx = 0.0f;
    #pragma unroll
    for (int dy = -1; dy <= 1; ++dy) {
        int yy = y + dy;
        if (yy < 0 || yy >= HH) continue;
        #pragma unroll
        for (int dx = -1; dx <= 1; ++dx) {
            int xx = x + dx;
            if (xx < 0 || xx >= WW) continue;
            int jj = yy * WW + xx;
            float v0 = low[jj], v1 = cur[jj], v2 = high[jj];
            float ssum = v0 + v1 + v2;
            den += ssum;
            nz += -0.5f * v0 + 0.5f * v1 + 1.5f * v2;
            ny += ccw[dy + 1] * ssum;
            nx += ccw[dx + 1] * ssum;
        }
    }
    float inv = 1.0f / (den + EPS_DIV);
    float s_n = (nz * inv) * (1.0f / 2048.0f);
    float y_n = (ny * inv + (float)y) * (1.0f / 2048.0f);
    float x_n = (nx * inv + (float)x) * (1.0f / 2048.0f);
    float a0 = aff[idx], a1 = aff[NPIX + idx], a2 = aff[2 * NPIX + idx], a3 = aff[3 * NPIX + idx];
    laf[0] = s_n * a0; laf[1] = s_n * a1; laf[2] = x_n;
    laf[3] = s_n * a2; laf[4] = s_n * a3; laf[5] = y_n;
}

extern "C" void kernel_launch(void* const* d_in, const int* in_sizes, int n_in,
                              void* d_out, int out_size, void* d_ws, size_t ws_size,
                              hipStream_t stream) {
    const float* low  = (const float*)d_in[0];
    const float* cur  = (const float*)d_in[1];
    const float* high = (const float*)d_in[2];
    const float* aff  = (const float*)d_in[3];
    const float* oct  = (const float*)d_in[4];
    int K = (out_size - NPIX) / 7;   // 4096
    float* out = (float*)d_out;

    char* ws = (char*)d_ws;
    unsigned int* cnt  = (unsigned int*)ws;
    unsigned int* hist = (unsigned int*)(ws + 128);
    u64* SG            = (u64*)(ws + 16384);
    const size_t cand_off = 81920;
    u64* cand          = (u64*)(ws + cand_off);
    size_t cap_sz = ws_size > cand_off ? (ws_size - cand_off) / 8 : 0;
    if (cap_sz > (size_t)NPIX) cap_sz = (size_t)NPIX;
    unsigned int cap = (unsigned int)cap_sz;

    hipMemsetAsync(ws, 0, 128, stream);   // cnt + barrier counters (hist zeroed in-kernel)

    dim3 gb(WW / 1024, HH / ROWS, 1);
    nms_map_kernel<<<gb, 256, 0, stream>>>(low, cur, high, oct, out + (size_t)7 * K,
                                           out, 7 * K, cand, cnt, cap);
    select_kernel<<<SEL_BLOCKS, 256, 0, stream>>>(cand, SG, cnt, hist, cap, K);
    rank_finalize_kernel<<<SG_CAP / 4, 256, 0, stream>>>(SG, cnt, low, cur, high, aff, out, K);
}

// Round 7
// 203.694 us; speedup vs baseline: 1.0408x; 1.0408x over previous
//
#include <hip/hip_runtime.h>
#include <cstdint>
#include <cstddef>

#define HH 2048
#define WW 2048
#define NPIX (HH * WW)
#define EPS_NMS 1e-5f
#define EPS_DIV 1e-8f
#define NEG_INF (-3.402823466e+38f)
#define ROWS 8          // rows per block (block covers 1024 cols x ROWS rows)
#define LCAP 2048       // per-block candidate cap (worst-case 1 per 2x2 = 2048)
#define SG_CAP 8192     // max selected (top22 >= T22) keys
#define NBIN 2048       // 11-bit radix bins
#define SEL_BLOCKS 64   // co-resident: 64 blocks x 4 waves
#define RB_ELEMS 32     // elements ranked per block in rank_finalize

typedef unsigned long long u64;

// ---- workspace layout (bytes) ----
// [0,   128)    : uint32 cnt[32]  0=n_cand 1=n_sel 3=prefix/T22 16..20=grid barrier ctrs
// [128, 8320)   : uint32 hist[2048]
// [16384,81920) : SG u64[8192]  (all keys with top22 >= T22, unsorted)
// [81920, ...)  : candidates u64[cap]

__device__ __forceinline__ float max3(float a, float b, float c) {
    return fmaxf(a, fmaxf(b, c));
}

__device__ __forceinline__ unsigned int aload(const unsigned int* p) {
    return __hip_atomic_load(p, __ATOMIC_RELAXED, __HIP_MEMORY_SCOPE_AGENT);
}

// grid barrier for exactly SEL_BLOCKS co-resident blocks; ctr pre-zeroed, single-use
__device__ __forceinline__ void gbar(unsigned int* ctr) {
    __syncthreads();
    if (threadIdx.x == 0) {
        __threadfence();
        atomicAdd(ctr, 1u);
        while (aload(ctr) < (unsigned int)SEL_BLOCKS) {}
        __threadfence();
    }
    __syncthreads();
}

// Software-pipelined rolling-row NMS: block = 256 threads x 4 cols = 1024 cols,
// ROWS rows. Row loads double-buffered one row ahead; halo via wave shfl.
__global__ __launch_bounds__(256) void nms_map_kernel(
    const float* __restrict__ low, const float* __restrict__ cur,
    const float* __restrict__ high, const float* __restrict__ oct,
    float* __restrict__ oct_out, float* __restrict__ vals_out, int n7k,
    u64* __restrict__ cand, unsigned int* __restrict__ cnt, unsigned int cap)
{
    __shared__ unsigned int lcount, lbase;
    __shared__ u64 lcand[LCAP];

    const int tid = threadIdx.x;
    const int lane = tid & 63;
    const int x4 = blockIdx.x * 1024 + tid * 4;
    const int y0 = blockIdx.y * ROWS;
    if (tid == 0) lcount = 0u;

    if (blockIdx.y == 0) {                    // fold in out-region zeroing
        int n4 = n7k >> 2;
        float4* vz = (float4*)vals_out;
        for (int i = blockIdx.x * 256 + tid; i < n4; i += gridDim.x * 256)
            vz[i] = make_float4(0.f, 0.f, 0.f, 0.f);
    }
    __syncthreads();

    float4 Lb[2], Cb[2], Hb[2], Ob[2];
    float eLl[2], eLc[2], eLh[2], eRl[2], eRc[2], eRh[2];

    // issue z-cube loads for row t into buffer slot
    #define ISSUE(t, slot) {                                                      \
        int tt = (t);                                                             \
        if (tt >= 0 && tt < HH) {                                                 \
            int jj = tt * WW + x4;                                                \
            Lb[slot] = *(const float4*)(low  + jj);                               \
            Cb[slot] = *(const float4*)(cur  + jj);                               \
            Hb[slot] = *(const float4*)(high + jj);                               \
            bool doL = (lane == 0)  && (x4 > 0);                                  \
            bool doR = (lane == 63) && (x4 + 4 < WW);                             \
            eLl[slot] = doL ? low[jj - 1]  : NEG_INF;                             \
            eLc[slot] = doL ? cur[jj - 1]  : NEG_INF;                             \
            eLh[slot] = doL ? high[jj - 1] : NEG_INF;                             \
            eRl[slot] = doR ? low[jj + 4]  : NEG_INF;                             \
            eRc[slot] = doR ? cur[jj + 4]  : NEG_INF;                             \
            eRh[slot] = doR ? high[jj + 4] : NEG_INF;                             \
        } else {                                                                  \
            Lb[slot] = Cb[slot] = Hb[slot] =                                      \
                make_float4(NEG_INF, NEG_INF, NEG_INF, NEG_INF);                  \
            eLl[slot] = eLc[slot] = eLh[slot] = NEG_INF;                          \
            eRl[slot] = eRc[slot] = eRh[slot] = NEG_INF;                          \
        }                                                                         \
    }

    // horizontal 3-window max of z-max from buffer slot
    #define CONSUME(slot, hzO, cvO) {                                             \
        float4 l = Lb[slot], c = Cb[slot], hh = Hb[slot];                         \
        float4 z;                                                                 \
        z.x = max3(l.x, c.x, hh.x);                                               \
        z.y = max3(l.y, c.y, hh.y);                                               \
        z.z = max3(l.z, c.z, hh.z);                                               \
        z.w = max3(l.w, c.w, hh.w);                                               \
        float zeL = max3(eLl[slot], eLc[slot], eLh[slot]);                        \
        float zeR = max3(eRl[slot], eRc[slot], eRh[slot]);                        \
        float zl = __shfl_up(z.w, 1, 64);                                         \
        float zr = __shfl_down(z.x, 1, 64);                                       \
        if (lane == 0)  zl = zeL;                                                 \
        if (lane == 63) zr = zeR;                                                 \
        hzO.x = max3(zl,  z.x, z.y);                                              \
        hzO.y = max3(z.x, z.y, z.z);                                              \
        hzO.z = max3(z.y, z.z, z.w);                                              \
        hzO.w = max3(z.z, z.w, zr);                                               \
        cvO = c;                                                                  \
    }

    float4 hzA, hzB, hzC, cvB, cvC, cvT;
    ISSUE(y0 - 1, 0)
    ISSUE(y0,     1)
    Ob[0] = *(const float4*)(oct + y0 * WW + x4);
    CONSUME(0, hzA, cvT)
    ISSUE(y0 + 1, 0)
    CONSUME(1, hzB, cvB)

    #pragma unroll
    for (int j = 0; j < ROWS; ++j) {
        int y = y0 + j;
        // prefetch row y+2 cube and row y+1 oct into the freed slots
        ISSUE(y + 2, (j + 1) & 1)
        if (j + 1 < ROWS)
            Ob[(j + 1) & 1] = *(const float4*)(oct + (y + 1) * WW + x4);
        CONSUME(j & 1, hzC, cvC)

        int idx = y * WW + x4;
        float4 o = Ob[j & 1];
        bool yin = (y > 0) && (y < HH - 1);
        float4 ov;
        #define DO_COMP(comp, i)  {                                               \
            float m = max3(hzA.comp, hzB.comp, hzC.comp);                         \
            int xg = x4 + (i);                                                    \
            bool interior = yin && (xg > 0) && (xg < WW - 1);                     \
            float nm = (((cvB.comp - m + EPS_NMS) > 0.0f) && interior)            \
                       ? cvB.comp * (1.0f - o.comp) : 0.0f;                       \
            ov.comp = (float)((unsigned char)(o.comp + nm));                      \
            if (nm > 0.0f) {                                                      \
                unsigned int p = atomicAdd(&lcount, 1u);                          \
                if (p < LCAP)                                                     \
                    lcand[p] = (((u64)__float_as_uint(nm)) << 32)                 \
                               | (unsigned int)(~(idx + (i)));                    \
            }                                                                     \
        }
        DO_COMP(x, 0) DO_COMP(y, 1) DO_COMP(z, 2) DO_COMP(w, 3)
        #undef DO_COMP
        *(float4*)(oct_out + idx) = ov;
        hzA = hzB; hzB = hzC; cvB = cvC;
    }
    #undef ISSUE
    #undef CONSUME

    __syncthreads();
    unsigned int c = lcount < LCAP ? lcount : LCAP;
    if (tid == 0) lbase = atomicAdd(cnt, c);
    __syncthreads();
    unsigned int base = lbase;
    for (unsigned int i = tid; i < c; i += 256) {
        unsigned int p = base + i;
        if (p < cap) cand[p] = lcand[i];
    }
}

// Fused exact top-K threshold select: 2 x 11-bit radix passes + compact,
// one launch, SEL_BLOCKS co-resident blocks, spin grid barriers.
__global__ __launch_bounds__(256) void select_kernel(
    const u64* __restrict__ cand, u64* __restrict__ SG,
    unsigned int* __restrict__ cnt, unsigned int* __restrict__ hist,
    unsigned int cap, int K)
{
    __shared__ unsigned int h[NBIN];
    __shared__ unsigned int s[256];
    __shared__ unsigned int sh_prefix, sh_remk;
    __shared__ unsigned int lc, lb;
    __shared__ u64 buf[2048];
    const int tid = threadIdx.x;
    const int bid = blockIdx.x;
    unsigned int* bar = cnt + 16;
    unsigned int n = cnt[0]; if (n > cap) n = cap;
    const unsigned int stride = SEL_BLOCKS * 256;

    // A: zero global hist (blocks 0..7) + local hist
    int gtid = bid * 256 + tid;
    if (gtid < NBIN) hist[gtid] = 0u;
    for (int i = tid; i < NBIN; i += 256) h[i] = 0u;
    __syncthreads();

    // B: pass-0 local hist on top 11 bits of value
    for (unsigned int i = bid * 256 + tid; i < n; i += stride)
        atomicAdd(&h[(unsigned int)(cand[i] >> 53)], 1u);
    gbar(&bar[0]);
    for (int i = tid; i < NBIN; i += 256) { unsigned int v = h[i]; if (v) atomicAdd(&hist[i], v); }
    gbar(&bar[1]);

    // F: pick pass 0 (block 0); thread t owns bins [t*8, t*8+8)
    if (bid == 0) {
        unsigned int bins[8], csum = 0;
        #pragma unroll
        for (int i = 0; i < 8; ++i) { bins[i] = aload(&hist[tid * 8 + i]); csum += bins[i]; }
        s[tid] = csum;
        __syncthreads();
        for (int off = 1; off < 256; off <<= 1) {
            unsigned int v = (tid + off < 256) ? s[tid + off] : 0u;
            __syncthreads(); s[tid] += v; __syncthreads();
        }
        unsigned int remk = (unsigned int)K;
        unsigned int incl = s[tid], excl = incl - csum, total = s[0];
        if (incl >= remk && excl < remk) {
            unsigned int cum = excl; int b = 7;
            for (; b > 0; --b) { cum += bins[b]; if (cum >= remk) break; }
            if (cum < remk) cum += bins[0];
            sh_prefix = (unsigned int)(tid * 8 + b);
            sh_remk   = remk - (cum - bins[b]);
        }
        if (tid == 0 && total < remk) { sh_prefix = 0u; sh_remk = remk; }
        __syncthreads();
        for (int i = tid; i < NBIN; i += 256) hist[i] = 0u;   // re-zero for pass 1
        __syncthreads();
        if (tid == 0) atomicExch(&cnt[3], sh_prefix);          // publish prefix
    }
    gbar(&bar[2]);

    // H: pass-1 local hist on next 11 bits, gated by prefix
    unsigned int prefix = aload(&cnt[3]);
    for (int i = tid; i < NBIN; i += 256) h[i] = 0u;
    __syncthreads();
    for (unsigned int i = bid * 256 + tid; i < n; i += stride) {
        unsigned int k32 = (unsigned int)(cand[i] >> 32);
        if ((k32 >> 21) == prefix) atomicAdd(&h[(k32 >> 10) & (NBIN - 1u)], 1u);
    }
    __syncthreads();
    for (int i = tid; i < NBIN; i += 256) { unsigned int v = h[i]; if (v) atomicAdd(&hist[i], v); }
    gbar(&bar[3]);

    // J: pick pass 1 (block 0) -> T22
    if (bid == 0) {
        unsigned int bins[8], csum = 0;
        #pragma unroll
        for (int i = 0; i < 8; ++i) { bins[i] = aload(&hist[tid * 8 + i]); csum += bins[i]; }
        s[tid] = csum;
        __syncthreads();
        for (int off = 1; off < 256; off <<= 1) {
            unsigned int v = (tid + off < 256) ? s[tid + off] : 0u;
            __syncthreads(); s[tid] += v; __syncthreads();
        }
        unsigned int remk = sh_remk, pfx = sh_prefix;
        unsigned int incl = s[tid], excl = incl - csum, total = s[0];
        __shared__ unsigned int sh_T;
        if (tid == 0) sh_T = pfx << 11;                        // degenerate default
        __syncthreads();
        if (incl >= remk && excl < remk) {
            unsigned int cum = excl; int b = 7;
            for (; b > 0; --b) { cum += bins[b]; if (cum >= remk) break; }
            if (cum < remk) cum += bins[0];
            sh_T = (pfx << 11) | (unsigned int)(tid * 8 + b);
        }
        __syncthreads();
        if (tid == 0) atomicExch(&cnt[3], sh_T);               // publish T22
    }
    gbar(&bar[4]);

    // L: compact all keys with top22 >= T22 into SG
    unsigned int T = aload(&cnt[3]);
    if (tid == 0) lc = 0u;
    __syncthreads();
    for (unsigned int i = bid * 256 + tid; i < n; i += stride) {
        u64 key = cand[i];
        if ((unsigned int)(key >> 42) >= T) {
            unsigned int p = atomicAdd(&lc, 1u);
            if (p < 2048u) buf[p] = key;
        }
    }
    __syncthreads();
    unsigned int c = lc < 2048u ? lc : 2048u;
    if (tid == 0) lb = atomicAdd(&cnt[1], c);
    __syncthreads();
    unsigned int base = lb;
    for (unsigned int i = tid; i < c; i += 256) {
        unsigned int p = base + i;
        if (p < SG_CAP) SG[p] = buf[i];
    }
}

// RB_ELEMS elements per block: stage SG into LDS once, each wave ranks 8 keys
// per scan pass (8 compares amortize each ds_read), then 32 lanes finalize.
__global__ __launch_bounds__(256) void rank_finalize_kernel(
    const u64* __restrict__ SG, const unsigned int* __restrict__ cnt,
    const float* __restrict__ low, const float* __restrict__ cur,
    const float* __restrict__ high, const float* __restrict__ aff,
    float* __restrict__ out, int K)
{
    __shared__ u64 s[SG_CAP];
    __shared__ unsigned int rnk[RB_ELEMS];
    unsigned int m = cnt[1]; if (m > SG_CAP) m = SG_CAP;
    unsigned int base = blockIdx.x * RB_ELEMS;
    if (base >= m) return;
    for (unsigned int i = threadIdx.x; i < m; i += 256) s[i] = SG[i];
    __syncthreads();

    unsigned int wave = threadIdx.x >> 6, lane = threadIdx.x & 63u;
    u64 my[8];
    unsigned int r[8];
    #pragma unroll
    for (int i = 0; i < 8; ++i) {
        unsigned int e = base + wave * 8 + i;
        my[i] = (e < m) ? s[e] : ~0ull;
        r[i] = 0u;
    }
    for (unsigned int j = lane; j < m; j += 64) {
        u64 key = s[j];
        #pragma unroll
        for (int i = 0; i < 8; ++i) r[i] += (unsigned)(key > my[i]);
    }
    #pragma unroll
    for (int i = 0; i < 8; ++i) {
        #pragma unroll
        for (int off = 32; off > 0; off >>= 1)
            r[i] += __shfl_down(r[i], off, 64);
        if (lane == 0) rnk[wave * 8 + i] = r[i];
    }
    __syncthreads();

    int i = threadIdx.x;
    if (i >= RB_ELEMS) return;
    unsigned int e = base + (unsigned int)i;
    if (e >= m) return;
    unsigned int rank = rnk[i];
    if (rank >= (unsigned int)K) return;
    u64 my_key = s[e];

    float val = __uint_as_float((unsigned int)(my_key >> 32));
    unsigned int idx = ~((unsigned int)my_key);
    out[rank] = val;
    float* laf = out + K + (size_t)rank * 6;
    int y = (int)(idx >> 11), x = (int)(idx & (WW - 1));
    const float ccw[3] = {-0.5f, 0.5f, 1.5f};
    float den = 0.0f, nz = 0.0f, ny = 0.0f, nx = 0.0f;
    #pragma unroll
    for (int dy = -1; dy <= 1; ++dy) {
        int yy = y + dy;
        if (yy < 0 || yy >= HH) continue;
        #pragma unroll
        for (int dx = -1; dx <= 1; ++dx) {
            int xx = x + dx;
            if (xx < 0 || xx >= WW) continue;
            int jj = yy * WW + xx;
            float v0 = low[jj], v1 = cur[jj], v2 = high[jj];
            float ssum = v0 + v1 + v2;
            den += ssum;
            nz += -0.5f * v0 + 0.5f * v1 + 1.5f * v2;
            ny += ccw[dy + 1] * ssum;
            nx += ccw[dx + 1] * ssum;
        }
    }
    float inv = 1.0f / (den + EPS_DIV);
    float s_n = (nz * inv) * (1.0f / 2048.0f);
    float y_n = (ny * inv + (float)y) * (1.0f / 2048.0f);
    float x_n = (nx * inv + (float)x) * (1.0f / 2048.0f);
    float a0 = aff[idx], a1 = aff[NPIX + idx], a2 = aff[2 * NPIX + idx], a3 = aff[3 * NPIX + idx];
    laf[0] = s_n * a0; laf[1] = s_n * a1; laf[2] = x_n;
    laf[3] = s_n * a2; laf[4] = s_n * a3; laf[5] = y_n;
}

extern "C" void kernel_launch(void* const* d_in, const int* in_sizes, int n_in,
                              void* d_out, int out_size, void* d_ws, size_t ws_size,
                              hipStream_t stream) {
    const float* low  = (const float*)d_in[0];
    const float* cur  = (const float*)d_in[1];
    const float* high = (const float*)d_in[2];
    const float* aff  = (const float*)d_in[3];
    const float* oct  = (const float*)d_in[4];
    int K = (out_size - NPIX) / 7;   // 4096
    float* out = (float*)d_out;

    char* ws = (char*)d_ws;
    unsigned int* cnt  = (unsigned int*)ws;
    unsigned int* hist = (unsigned int*)(ws + 128);
    u64* SG            = (u64*)(ws + 16384);
    const size_t cand_off = 81920;
    u64* cand          = (u64*)(ws + cand_off);
    size_t cap_sz = ws_size > cand_off ? (ws_size - cand_off) / 8 : 0;
    if (cap_sz > (size_t)NPIX) cap_sz = (size_t)NPIX;
    unsigned int cap = (unsigned int)cap_sz;

    hipMemsetAsync(ws, 0, 128, stream);   // cnt + barrier counters (hist zeroed in-kernel)

    dim3 gb(WW / 1024, HH / ROWS, 1);
    nms_map_kernel<<<gb, 256, 0, stream>>>(low, cur, high, oct, out + (size_t)7 * K,
                                           out, 7 * K, cand, cnt, cap);
    select_kernel<<<SEL_BLOCKS, 256, 0, stream>>>(cand, SG, cnt, hist, cap, K);
    rank_finalize_kernel<<<SG_CAP / RB_ELEMS, 256, 0, stream>>>(SG, cnt, low, cur, high, aff, out, K);
}